// Round 17
// baseline (154.195 us; speedup 1.0000x reference)
//
#include <hip/hip_runtime.h>
#include <math.h>

#define T_TOTAL 262144
#define HIDN 20
#define IND 9

// ---- geometry: TWO chunks per wave (ILP fills the 28% correlated-stall
// idle R16 measured; TLP falsified in R13). 4 waves/WG, 512 WGs -> 2 WG/CU,
// 2 waves/SIMD x 2 streams = 4 independent chains per SIMD. Weight registers
// (the dominant state) are SHARED between the streams.
#define CHUNK 64
#define WARM 12
#define NROWS (WARM + CHUNK + 2)        // 78 staged rows per stream
#define NCHUNK (T_TOTAL / CHUNK)        // 4096 chunks
#define NPAIR (NCHUNK / 2)              // 2048 (stream B = stream A + NPAIR)
#define WAVES_PER_BLK 4
#define NWG (NPAIR / WAVES_PER_BLK)     // 512

#define L2E 1.44269504088896340736f

typedef float float4v  __attribute__((ext_vector_type(4)));
typedef float float2v  __attribute__((ext_vector_type(2)));
typedef unsigned int uint4v __attribute__((ext_vector_type(4)));
typedef unsigned int uint2v __attribute__((ext_vector_type(2)));
typedef _Float16 h2v   __attribute__((ext_vector_type(2)));

// prescaled activations: weights/biases carry log2e (i,f,o) or 2*log2e (g)
__device__ __forceinline__ float sig2(float a) {
    return __builtin_amdgcn_rcpf(1.0f + __builtin_amdgcn_exp2f(-a));
}
__device__ __forceinline__ float tanh2g(float a) {
    return 1.0f - 2.0f * __builtin_amdgcn_rcpf(1.0f + __builtin_amdgcn_exp2f(a));
}
__device__ __forceinline__ float tanhfst(float x) {
    return 1.0f - 2.0f * __builtin_amdgcn_rcpf(
        1.0f + __builtin_amdgcn_exp2f(2.0f * L2E * x));
}

// v_dot2_f32_f16: 2 f16 MACs, f32 accumulate (R9 lever)
__device__ __forceinline__ float fd2(h2v a, unsigned b, float c) {
    return __builtin_amdgcn_fdot2(a, __builtin_bit_cast(h2v, b), c, false);
}
__device__ __forceinline__ h2v pk2(float a, float b) {
    return __builtin_bit_cast(h2v, __builtin_amdgcn_cvt_pkrtz(a, b));
}
__device__ __forceinline__ h2v h2zero() {
    return __builtin_bit_cast(h2v, 0u);
}

// wave64 sum via DPP (verified R12); ctrl/masks must be immediates.
template<int CTRL, int RMASK>
__device__ __forceinline__ float dpp_add(float v) {
    int t = __builtin_amdgcn_update_dpp(0, __builtin_bit_cast(int, v),
                                        CTRL, RMASK, 0xf, true);
    return v + __builtin_bit_cast(float, t);
}
__device__ __forceinline__ float wave_sum63(float v) {
    v = dpp_add<0x111, 0xf>(v);   // row_shr:1
    v = dpp_add<0x112, 0xf>(v);   // row_shr:2
    v = dpp_add<0x114, 0xf>(v);   // row_shr:4
    v = dpp_add<0x118, 0xf>(v);   // row_shr:8
    v = dpp_add<0x142, 0xa>(v);   // row_bcast:15 -> rows 1,3
    v = dpp_add<0x143, 0xc>(v);   // row_bcast:31 -> rows 2,3
    return v;                     // lane 63 holds the total
}

// per-wave DS ops execute in order; compile-time barrier suffices (R6+).
#define LDS_ORDER() asm volatile("" ::: "memory")

// ============================================================================
// Lane roles (both streams): 0-19 L1 unit k | 20-39 L2 W_ih2 half (state
// owner, + xg gates i,f) | 40-59 L2 W_hh2 half (+ xg gates g,o) | 60-63 idle.
// Per-wave LDS (u32): xlsA 624 | xlsB 624 | hcA 32 | hcB 32 | ringA 160 |
// ringB 160 | scratch 128 = 1760 u32 = 7040 B -> 28160 B/WG (2 WG/CU).
// Chunk-0 exactness: stream A of wave 0 runs the uniform loop with R6's
// verified resets at sA==0 (full zero) and sA==1 (L2-state zero); its
// pre-reset steps consume low-clamped x rows and are wiped.
// ============================================================================
#define XLSA_OFF  0
#define XLSB_OFF  (NROWS * 8)                   // 624
#define HCA_OFF   (2 * NROWS * 8)               // 1248
#define HCB_OFF   (HCA_OFF + 32)                // 1280
#define RINGA_OFF (HCB_OFF + 32)                // 1312
#define RINGB_OFF (RINGA_OFF + 160)             // 1472
#define SCR_OFF   (RINGB_OFF + 160)             // 1632
#define WAVE_LDS_U32 (SCR_OFF + 128)            // 1760 u32 = 7040 B

// h-weights (w_hh1 / w_ih2 / w_hh2 rows), prescaled per gate, f16-packed
#define DECLWF(q) float4v wv##q##0, wv##q##1, wv##q##2, wv##q##3, wv##q##4; float bq##q;
#define LOADWF(q) { \
    const float ws_ = ((q) == 2) ? (2.0f * L2E) : L2E; \
    const float fs_ = scale * ws_; \
    const float4v* wr = (const float4v*)(wbase + ((q) * HIDN + krow) * HIDN); \
    wv##q##0 = fs_ * wr[0]; wv##q##1 = fs_ * wr[1]; wv##q##2 = fs_ * wr[2]; \
    wv##q##3 = fs_ * wr[3]; wv##q##4 = fs_ * wr[4]; \
    bq##q = ws_ * ((grp == 0) ? b1[(q) * HIDN + k] \
                 : ((grp == 1) ? b2[(q) * HIDN + k] : 0.0f)); \
}
#define DECLWH(q) h2v w##q##0, w##q##1, w##q##2, w##q##3, w##q##4, \
                      w##q##5, w##q##6, w##q##7, w##q##8, w##q##9;
#define PACKW(q) { \
    w##q##0 = pk2(wv##q##0[0], wv##q##0[1]); w##q##1 = pk2(wv##q##0[2], wv##q##0[3]); \
    w##q##2 = pk2(wv##q##1[0], wv##q##1[1]); w##q##3 = pk2(wv##q##1[2], wv##q##1[3]); \
    w##q##4 = pk2(wv##q##2[0], wv##q##2[1]); w##q##5 = pk2(wv##q##2[2], wv##q##2[3]); \
    w##q##6 = pk2(wv##q##3[0], wv##q##3[1]); w##q##7 = pk2(wv##q##3[2], wv##q##3[3]); \
    w##q##8 = pk2(wv##q##4[0], wv##q##4[1]); w##q##9 = pk2(wv##q##4[2], wv##q##4[3]); \
}

// 20-wide h-dot for gate q, stream S: two independent 5-deep fd2 chains
#define DOTH(S, acc, q) { \
    float accB_ = fd2(w##q##5, rb##S[1], 0.0f); \
    acc = fd2(w##q##0, ra##S[0], acc); \
    accB_ = fd2(w##q##6, rb##S[2], accB_); \
    acc = fd2(w##q##1, ra##S[1], acc); \
    accB_ = fd2(w##q##7, rb##S[3], accB_); \
    acc = fd2(w##q##2, ra##S[2], acc); \
    accB_ = fd2(w##q##8, rc##S[0], accB_); \
    acc = fd2(w##q##3, ra##S[3], acc); \
    accB_ = fd2(w##q##9, rc##S[1], accB_); \
    acc = fd2(w##q##4, rb##S[0], acc); \
    acc += accB_; \
}

// xg pipeline for stream S: lanes 20-59 compute xg row (i_+1) -> ring slot
#define XPIPE(S, i_) { \
    const unsigned* xrow_ = xls##S + ((i_) + 1) * 8; \
    uint4v xa = *(const uint4v*)xrow_; \
    unsigned xc = xrow_[4]; \
    float xp0_ = fd2(xwA0, xa[0], 0.0f); \
    xp0_ = fd2(xwA1, xa[1], xp0_); xp0_ = fd2(xwA2, xa[2], xp0_); \
    xp0_ = fd2(xwA3, xa[3], xp0_); xp0_ = fd2(xwA4, xc, xp0_); \
    float xp1_ = fd2(xwB0, xa[0], 0.0f); \
    xp1_ = fd2(xwB1, xa[1], xp1_); xp1_ = fd2(xwB2, xa[2], xp1_); \
    xp1_ = fd2(xwB3, xa[3], xp1_); xp1_ = fd2(xwB4, xc, xp1_); \
    float2v wv2_; wv2_[0] = xp0_; wv2_[1] = xp1_; \
    *(float2v*)(xg_wb##S + (((i_) + 1) & 1) * pstride) = wv2_; \
}

// one LSTM step for stream S at unified index i_ (no trailing fence; one
// LDS_ORDER per dual-step suffices — streams touch disjoint addresses)
#define STEP_CORE(S, i_) { \
    const int rsel_ = ((i_) & 1) * 80; \
    float2v g01 = *(const float2v*)(ring##S + rsel_ + rk2); \
    float2v g23 = *(const float2v*)(ring##S + rsel_ + 40 + rk2); \
    uint4v ra##S = *(const uint4v*)(hu##S); \
    uint4v rb##S = *(const uint4v*)(hu##S + 4); \
    uint2v rc##S = *(const uint2v*)(hu##S + 8); \
    float a0 = fmaf(m1, g01[0], bq0); \
    float a1 = fmaf(m1, g01[1], bq1); \
    float a2 = fmaf(m1, g23[0], bq2); \
    float a3 = fmaf(m1, g23[1], bq3); \
    DOTH(S, a0, 0) DOTH(S, a1, 1) DOTH(S, a2, 2) DOTH(S, a3, 3) \
    XPIPE(S, i_) \
    a0 = fmaf(m2, __shfl(a0, shsrc, 64), a0); \
    a1 = fmaf(m2, __shfl(a1, shsrc, 64), a1); \
    a2 = fmaf(m2, __shfl(a2, shsrc, 64), a2); \
    a3 = fmaf(m2, __shfl(a3, shsrc, 64), a3); \
    float gi = sig2(a0), gf = sig2(a1), gg = tanh2g(a2), go = sig2(a3); \
    c##S = fmaf(gf, c##S, gi * gg); \
    h##S = go * tanhfst(c##S); \
    if (lane < 40) hc16##S[hidx16] = (_Float16)h##S; \
}

// chunk-0 resets for stream A (R6-verified; fires only on the chA==0 wave):
// sA==0 -> full zero (pre-reset garbage wiped); sA==1 -> L2-state zero.
#define RESET_A(i_) { \
    const int sA_ = startvA + (i_); \
    if (__builtin_expect(sA_ == 0, 0)) { \
        cA = 0.0f; hA = 0.0f; \
        if (lane < 32) hc32A[lane] = 0u; \
        LDS_ORDER(); \
    } else if (__builtin_expect(sA_ == 1, 0)) { \
        cA *= m1; hA *= m1; \
        if (lane < 40) hc16A[hidx16] = (_Float16)hA; \
        LDS_ORDER(); \
    } \
}

__global__ __launch_bounds__(256) __attribute__((amdgpu_waves_per_eu(2)))
void lstm_fused7(const float* __restrict__ x,
                 const float* __restrict__ w_ih1, const float* __restrict__ w_hh1,
                 const float* __restrict__ b1,
                 const float* __restrict__ w_ih2, const float* __restrict__ w_hh2,
                 const float* __restrict__ b2,
                 const float* __restrict__ w_p, const float* __restrict__ b_p,
                 float* __restrict__ out)
{
    __shared__ __align__(16) unsigned smem[WAVES_PER_BLK * WAVE_LDS_U32]; // 28160 B

    const int tid  = threadIdx.x;
    const int lane = tid & 63;
    const int wid  = __builtin_amdgcn_readfirstlane(tid >> 6);
    unsigned* wls   = smem + wid * WAVE_LDS_U32;
    unsigned* xlsA  = wls + XLSA_OFF;
    unsigned* xlsB  = wls + XLSB_OFF;
    unsigned* hc32A = wls + HCA_OFF;
    unsigned* hc32B = wls + HCB_OFF;
    unsigned* ringA = wls + RINGA_OFF;
    unsigned* ringB = wls + RINGB_OFF;
    _Float16* hc16A = (_Float16*)hc32A;
    _Float16* hc16B = (_Float16*)hc32B;

    const int chA = blockIdx.x * WAVES_PER_BLK + wid;      // [0, 2048)
    const int chB = chA + NPAIR;                           // [2048, 4096)
    const int t0A = chA * CHUNK;
    const int t0B = chB * CHUNK;
    const int startvA = t0A - WARM;                        // -12 only for chA==0
    const int startvB = t0B - WARM;                        // always > 0

    // ---- stage x rows for both streams as packed-f16 pairs (8 u32/row)
    for (int sl = lane; sl < NROWS * 5; sl += 64) {
        const int r = sl / 5;
        const int j = sl - r * 5;
        int gtA = startvA + r;
        gtA = (gtA < 0) ? 0 : gtA;
        int gtB = startvB + r;
        gtB = (gtB > T_TOTAL - 1) ? (T_TOTAL - 1) : gtB;
        const float* xrA = x + (size_t)gtA * IND + 2 * j;
        const float* xrB = x + (size_t)gtB * IND + 2 * j;
        const float vaA = xrA[0], vaB = xrB[0];
        const float vbA = (j < 4) ? xrA[1] : 0.0f;
        const float vbB = (j < 4) ? xrB[1] : 0.0f;
        xlsA[r * 8 + j] = __builtin_bit_cast(unsigned, pk2(vaA, vbA));
        xlsB[r * 8 + j] = __builtin_bit_cast(unsigned, pk2(vaB, vbB));
    }
    if (lane < 32) { hc32A[lane] = 0u; hc32B[lane] = 0u; }

    const int grp  = lane / 20;                    // 0..3 (grp3 = lanes 60-63)
    const int k    = lane - grp * 20;
    const int krow = (grp < 3) ? k : 0;
    const float scale = (grp < 3) ? 1.0f : 0.0f;
    const float* wbase = (grp == 1) ? w_ih2 : ((grp == 2) ? w_hh2 : w_hh1);

    DECLWF(0) DECLWF(1) DECLWF(2) DECLWF(3)
    LOADWF(0) LOADWF(1) LOADWF(2) LOADWF(3)
    DECLWH(0) DECLWH(1) DECLWH(2) DECLWH(3)
    PACKW(0) PACKW(1) PACKW(2) PACKW(3)

    // xg-pipeline weights: lane 20+k owns gates (0,1) of L1 unit k,
    // lane 40+k owns gates (2,3); prescaled; zero elsewhere. Shared by both
    // streams (the whole point of dual-chunk).
    h2v xwA0, xwA1, xwA2, xwA3, xwA4, xwB0, xwB1, xwB2, xwB3, xwB4;
    if (grp == 1 || grp == 2) {
        const int   gA = (grp == 1) ? 0 : 2;
        const float sA = (grp == 2) ? (2.0f * L2E) : L2E;
        const float sB = L2E;
        const float* rA = w_ih1 + (gA * HIDN + k) * IND;
        const float* rB = w_ih1 + ((gA + 1) * HIDN + k) * IND;
        xwA0 = pk2(sA * rA[0], sA * rA[1]); xwA1 = pk2(sA * rA[2], sA * rA[3]);
        xwA2 = pk2(sA * rA[4], sA * rA[5]); xwA3 = pk2(sA * rA[6], sA * rA[7]);
        xwA4 = pk2(sA * rA[8], 0.0f);
        xwB0 = pk2(sB * rB[0], sB * rB[1]); xwB1 = pk2(sB * rB[2], sB * rB[3]);
        xwB2 = pk2(sB * rB[4], sB * rB[5]); xwB3 = pk2(sB * rB[6], sB * rB[7]);
        xwB4 = pk2(sB * rB[8], 0.0f);
    } else {
        xwA0 = h2zero(); xwA1 = h2zero(); xwA2 = h2zero(); xwA3 = h2zero();
        xwA4 = h2zero(); xwB0 = h2zero(); xwB1 = h2zero(); xwB2 = h2zero();
        xwB3 = h2zero(); xwB4 = h2zero();
    }

    const unsigned* huA = hc32A + ((lane < 40) ? 0 : 16);
    const unsigned* huB = hc32B + ((lane < 40) ? 0 : 16);
    const bool  isl2   = (lane >= 20 && lane < 40);
    const float m2     = isl2 ? 1.0f : 0.0f;
    const float m1     = (grp == 0) ? 1.0f : 0.0f;
    const int   h2col  = lane - 20;
    const int   hidx16 = (lane < 20) ? lane : (32 + h2col);
    const int   shsrc  = (lane + 20) & 63;
    const int   rk2    = (grp == 0) ? (k * 2) : 0;

    // ring write bases (non-writers -> scratch, pstride 0)
    unsigned* xg_wbA = (grp == 1) ? (ringA + k * 2)
                     : (grp == 2) ? (ringA + 40 + k * 2)
                     : (wls + SCR_OFF + lane * 2);
    unsigned* xg_wbB = (grp == 1) ? (ringB + k * 2)
                     : (grp == 2) ? (ringB + 40 + k * 2)
                     : (wls + SCR_OFF + lane * 2);
    const int pstride = (grp == 1 || grp == 2) ? 80 : 0;

    const float wp = isl2 ? w_p[h2col] : 0.0f;
    const float bp = b_p[0];

    float cA = 0.0f, hA = 0.0f, cB = 0.0f, hB = 0.0f;
    LDS_ORDER();                 // staging + hc zeros ordered before reads

    // ---- pipeline prologue: xg row 0 -> ring slot 0, both streams
    XPIPE(A, -1)
    XPIPE(B, -1)
    LDS_ORDER();

    // ---- peel (i = 0) on zero state, both streams
    STEP_CORE(A, 0)
    STEP_CORE(B, 0)
    LDS_ORDER();
    // post-peel: zero the layer-2 chain state (layer 2 lags layer 1)
    cA *= m1; hA *= m1; cB *= m1; hB *= m1;
    if (lane < 40) { hc16A[hidx16] = (_Float16)hA; hc16B[hidx16] = (_Float16)hB; }
    LDS_ORDER();

    // ---- warm loop: 12 steps, both streams (uniform trip count; chunk-0
    // stream A runs on wiped-later garbage until its sA==0 reset at i=12)
#pragma unroll 4
    for (int i = 1; i <= WARM; ++i) {
        RESET_A(i)
        STEP_CORE(A, i)
        STEP_CORE(B, i)
        LDS_ORDER();
    }

    // ---- output loop: 64 steps; step j emits h2[t0+j-1] for both streams
#pragma unroll 4
    for (int j = 1; j <= CHUNK; ++j) {
        const int i = WARM + j;
        RESET_A(i)
        STEP_CORE(A, i)
        STEP_CORE(B, i)
        LDS_ORDER();
        float prA = wave_sum63(wp * hA);
        float prB = wave_sum63(wp * hB);
        if (lane == 63) {
            out[t0A + j - 1] = prA + bp;
            out[t0B + j - 1] = prB + bp;
        }
    }
}

extern "C" void kernel_launch(void* const* d_in, const int* in_sizes, int n_in,
                              void* d_out, int out_size, void* d_ws, size_t ws_size,
                              hipStream_t stream) {
    const float* x     = (const float*)d_in[0];
    const float* w_ih1 = (const float*)d_in[1];
    const float* w_hh1 = (const float*)d_in[2];
    const float* b1    = (const float*)d_in[3];
    const float* w_ih2 = (const float*)d_in[4];
    const float* w_hh2 = (const float*)d_in[5];
    const float* b2    = (const float*)d_in[6];
    const float* w_p   = (const float*)d_in[7];
    const float* b_p   = (const float*)d_in[8];
    float* out = (float*)d_out;
    (void)d_ws; (void)ws_size;   // fused kernel: no workspace needed

    lstm_fused7<<<NWG, 256, 0, stream>>>(x, w_ih1, w_hh1, b1,
                                         w_ih2, w_hh2, b2, w_p, b_p, out);
}

// Round 18
// 145.334 us; speedup vs baseline: 1.0610x; 1.0610x over previous
//
#include <hip/hip_runtime.h>
#include <math.h>

#define T_TOTAL 262144
#define HIDN 20
#define IND 9

// ---- geometry: R16 (session best: 145.8us harness / 84.9us dispatch).
// one chunk per wave, 4 waves/WG, 1024 WGs. WARM 12 (48->32->24->16->12 all
// bit-identical absmax). Dual-chunk ILP falsified twice (R5, R17: allocator
// compacts to 56 VGPR regardless -> streams serialize through register reuse).
#define CHUNK 64
#define WARM 12
#define NROWS (WARM + CHUNK + 2)        // 78 staged rows (+1 pipeline row)
#define NCHUNK (T_TOTAL / CHUNK)        // 4096 waves
#define WAVES_PER_BLK 4
#define NWG (NCHUNK / WAVES_PER_BLK)    // 1024

#define L2E 1.44269504088896340736f

typedef float float4v  __attribute__((ext_vector_type(4)));
typedef float float2v  __attribute__((ext_vector_type(2)));
typedef unsigned int uint4v __attribute__((ext_vector_type(4)));
typedef unsigned int uint2v __attribute__((ext_vector_type(2)));
typedef _Float16 h2v   __attribute__((ext_vector_type(2)));

// prescaled activations: weights/biases carry log2e (i,f,o) or 2*log2e (g)
__device__ __forceinline__ float sig2(float a) {        // a = log2e * preact
    return __builtin_amdgcn_rcpf(1.0f + __builtin_amdgcn_exp2f(-a));
}
__device__ __forceinline__ float tanh2g(float a) {      // a = 2*log2e * preact
    return 1.0f - 2.0f * __builtin_amdgcn_rcpf(1.0f + __builtin_amdgcn_exp2f(a));
}
__device__ __forceinline__ float tanhfst(float x) {     // unscaled input (c)
    return 1.0f - 2.0f * __builtin_amdgcn_rcpf(
        1.0f + __builtin_amdgcn_exp2f(2.0f * L2E * x));
}

// v_dot2_f32_f16: 2 f16 MACs, f32 accumulate (R9 lever)
__device__ __forceinline__ float fd2(h2v a, unsigned b, float c) {
    return __builtin_amdgcn_fdot2(a, __builtin_bit_cast(h2v, b), c, false);
}
__device__ __forceinline__ h2v pk2(float a, float b) {
    return __builtin_bit_cast(h2v, __builtin_amdgcn_cvt_pkrtz(a, b));
}
__device__ __forceinline__ h2v h2zero() {
    return __builtin_bit_cast(h2v, 0u);
}

// wave64 sum via DPP (verified R12); ctrl/masks must be immediates.
template<int CTRL, int RMASK>
__device__ __forceinline__ float dpp_add(float v) {
    int t = __builtin_amdgcn_update_dpp(0, __builtin_bit_cast(int, v),
                                        CTRL, RMASK, 0xf, true);
    return v + __builtin_bit_cast(float, t);
}
__device__ __forceinline__ float wave_sum63(float v) {
    v = dpp_add<0x111, 0xf>(v);   // row_shr:1
    v = dpp_add<0x112, 0xf>(v);   // row_shr:2
    v = dpp_add<0x114, 0xf>(v);   // row_shr:4
    v = dpp_add<0x118, 0xf>(v);   // row_shr:8
    v = dpp_add<0x142, 0xa>(v);   // row_bcast:15 -> rows 1,3
    v = dpp_add<0x143, 0xc>(v);   // row_bcast:31 -> rows 2,3
    return v;                     // lane 63 holds the total
}

// per-wave DS ops execute in order; compile-time barrier suffices (R6+).
#define LDS_ORDER() asm volatile("" ::: "memory")

// ============================================================================
// Lane roles: 0-19 L1 unit k | 20-39 L2 W_ih2 half (state owner, + xg gates
// i,f of L1 unit k) | 40-59 L2 W_hh2 half (+ xg gates g,o) | 60-63 idle/store.
// xg ring layout: [slot 0|1][plane (i,f)|(g,o)][unit k][2 f32] — stride-2-word
// b64 accesses (2-way max alias = free), non-L1 reads wave-uniform.
// Residual 1.3M bank conflicts = the 4 ds_bpermute (~0.6%/step, not worth it).
// Per-wave LDS (u32): xls 78x8=624 | hc 32 | ring 2x80=160 | scratch 128.
// ============================================================================
#define XLS_U32  (NROWS * 8)            // 624
#define HC_OFF   XLS_U32                // 624
#define RING_OFF (HC_OFF + 32)          // 656
#define SCR_OFF  (RING_OFF + 160)       // 816
#define WAVE_LDS_U32 (SCR_OFF + 128)    // 944 u32 = 3776 B -> 15104 B/WG

// h-weights (w_hh1 / w_ih2 / w_hh2 rows), prescaled per gate, f16-packed
#define DECLWF(q) float4v wv##q##0, wv##q##1, wv##q##2, wv##q##3, wv##q##4; float bq##q;
#define LOADWF(q) { \
    const float ws_ = ((q) == 2) ? (2.0f * L2E) : L2E; \
    const float fs_ = scale * ws_; \
    const float4v* wr = (const float4v*)(wbase + ((q) * HIDN + krow) * HIDN); \
    wv##q##0 = fs_ * wr[0]; wv##q##1 = fs_ * wr[1]; wv##q##2 = fs_ * wr[2]; \
    wv##q##3 = fs_ * wr[3]; wv##q##4 = fs_ * wr[4]; \
    bq##q = ws_ * ((grp == 0) ? b1[(q) * HIDN + k] \
                 : ((grp == 1) ? b2[(q) * HIDN + k] : 0.0f)); \
}
#define DECLWH(q) h2v w##q##0, w##q##1, w##q##2, w##q##3, w##q##4, \
                      w##q##5, w##q##6, w##q##7, w##q##8, w##q##9;
#define PACKW(q) { \
    w##q##0 = pk2(wv##q##0[0], wv##q##0[1]); w##q##1 = pk2(wv##q##0[2], wv##q##0[3]); \
    w##q##2 = pk2(wv##q##1[0], wv##q##1[1]); w##q##3 = pk2(wv##q##1[2], wv##q##1[3]); \
    w##q##4 = pk2(wv##q##2[0], wv##q##2[1]); w##q##5 = pk2(wv##q##2[2], wv##q##2[3]); \
    w##q##6 = pk2(wv##q##3[0], wv##q##3[1]); w##q##7 = pk2(wv##q##3[2], wv##q##3[3]); \
    w##q##8 = pk2(wv##q##4[0], wv##q##4[1]); w##q##9 = pk2(wv##q##4[2], wv##q##4[3]); \
}

// 20-wide h-dot for gate q: two independent 5-deep fd2 chains + 1 add
#define DOTH(acc, q) { \
    float accB_ = fd2(w##q##5, rb[1], 0.0f); \
    acc = fd2(w##q##0, ra[0], acc); \
    accB_ = fd2(w##q##6, rb[2], accB_); \
    acc = fd2(w##q##1, ra[1], acc); \
    accB_ = fd2(w##q##7, rb[3], accB_); \
    acc = fd2(w##q##2, ra[2], acc); \
    accB_ = fd2(w##q##8, rc[0], accB_); \
    acc = fd2(w##q##3, ra[3], acc); \
    accB_ = fd2(w##q##9, rc[1], accB_); \
    acc = fd2(w##q##4, rb[0], acc); \
    acc += accB_; \
}

// xg pipeline: compute the two owned gates of L1 unit k from x row (i_+1),
// write b64 into ring slot ((i_+1)&1), plane per group. Non-writer lanes hit
// the scratch area (pstride 0, zero weights) — branch-free.
#define XPIPE(i_) { \
    const unsigned* xrow_ = xls + ((i_) + 1) * 8; \
    uint4v xa = *(const uint4v*)xrow_; \
    unsigned xc = xrow_[4]; \
    float xp0_ = fd2(xwA0, xa[0], 0.0f); \
    xp0_ = fd2(xwA1, xa[1], xp0_); xp0_ = fd2(xwA2, xa[2], xp0_); \
    xp0_ = fd2(xwA3, xa[3], xp0_); xp0_ = fd2(xwA4, xc, xp0_); \
    float xp1_ = fd2(xwB0, xa[0], 0.0f); \
    xp1_ = fd2(xwB1, xa[1], xp1_); xp1_ = fd2(xwB2, xa[2], xp1_); \
    xp1_ = fd2(xwB3, xa[3], xp1_); xp1_ = fd2(xwB4, xc, xp1_); \
    float2v wv2_; wv2_[0] = xp0_; wv2_[1] = xp1_; \
    *(float2v*)(xg_wb + (((i_) + 1) & 1) * pstride) = wv2_; \
}

// one LSTM step consuming xg ring slot (i_&1) and h from LDS
#define STEP_P(i_) { \
    const int rsel_ = ((i_) & 1) * 80; \
    float2v g01 = *(const float2v*)(wls + RING_OFF + rsel_ + rk2); \
    float2v g23 = *(const float2v*)(wls + RING_OFF + rsel_ + 40 + rk2); \
    uint4v ra = *(const uint4v*)(hu); \
    uint4v rb = *(const uint4v*)(hu + 4); \
    uint2v rc = *(const uint2v*)(hu + 8); \
    float a0 = fmaf(m1, g01[0], bq0); \
    float a1 = fmaf(m1, g01[1], bq1); \
    float a2 = fmaf(m1, g23[0], bq2); \
    float a3 = fmaf(m1, g23[1], bq3); \
    DOTH(a0, 0) DOTH(a1, 1) DOTH(a2, 2) DOTH(a3, 3) \
    XPIPE(i_) \
    a0 = fmaf(m2, __shfl(a0, shsrc, 64), a0); \
    a1 = fmaf(m2, __shfl(a1, shsrc, 64), a1); \
    a2 = fmaf(m2, __shfl(a2, shsrc, 64), a2); \
    a3 = fmaf(m2, __shfl(a3, shsrc, 64), a3); \
    float gi = sig2(a0), gf = sig2(a1), gg = tanh2g(a2), go = sig2(a3); \
    c = fmaf(gf, c, gi * gg); \
    h = go * tanhfst(c); \
    if (lane < 40) hc16[hidx16] = (_Float16)h; \
    LDS_ORDER(); \
}

__global__ __launch_bounds__(256)
void lstm_fused6(const float* __restrict__ x,
                 const float* __restrict__ w_ih1, const float* __restrict__ w_hh1,
                 const float* __restrict__ b1,
                 const float* __restrict__ w_ih2, const float* __restrict__ w_hh2,
                 const float* __restrict__ b2,
                 const float* __restrict__ w_p, const float* __restrict__ b_p,
                 float* __restrict__ out)
{
    __shared__ __align__(16) unsigned smem[WAVES_PER_BLK * WAVE_LDS_U32]; // 15104 B

    const int tid  = threadIdx.x;
    const int lane = tid & 63;
    const int wid  = __builtin_amdgcn_readfirstlane(tid >> 6);
    unsigned* wls  = smem + wid * WAVE_LDS_U32;
    unsigned* xls  = wls;
    unsigned* hc32 = wls + HC_OFF;
    _Float16* hc16 = (_Float16*)hc32;

    const int ch     = blockIdx.x * WAVES_PER_BLK + wid;   // chunk id [0,4096)
    const int t0     = ch * CHUNK;
    const int startv = (t0 >= WARM) ? (t0 - WARM) : 0;     // clamped: >= 0
    const int nwarm  = t0 - startv;                        // 12 (0 for ch==0)
    const int nrows  = nwarm + CHUNK + 2;                  // staged rows

    // ---- stage x rows startv.. as packed-f16 pairs (stride 8 u32/row)
    for (int sl = lane; sl < nrows * 5; sl += 64) {
        const int r = sl / 5;
        const int j = sl - r * 5;
        int gt = startv + r;
        gt = (gt > T_TOTAL - 1) ? (T_TOTAL - 1) : gt;
        const float* xr = x + (size_t)gt * IND + 2 * j;
        const float va = xr[0];
        const float vb = (j < 4) ? xr[1] : 0.0f;   // j==4: x[8] + zero pad
        xls[r * 8 + j] = __builtin_bit_cast(unsigned, pk2(va, vb));
    }
    if (lane < 32) hc32[lane] = 0u;

    const int grp  = lane / 20;                    // 0..3 (grp3 = lanes 60-63)
    const int k    = lane - grp * 20;
    const int krow = (grp < 3) ? k : 0;
    const float scale = (grp < 3) ? 1.0f : 0.0f;
    const float* wbase = (grp == 1) ? w_ih2 : ((grp == 2) ? w_hh2 : w_hh1);

    DECLWF(0) DECLWF(1) DECLWF(2) DECLWF(3)
    LOADWF(0) LOADWF(1) LOADWF(2) LOADWF(3)
    DECLWH(0) DECLWH(1) DECLWH(2) DECLWH(3)
    PACKW(0) PACKW(1) PACKW(2) PACKW(3)

    // xg-pipeline weights: lane 20+k owns gates (0,1) of L1 unit k,
    // lane 40+k owns gates (2,3); all prescaled; zero elsewhere.
    h2v xwA0, xwA1, xwA2, xwA3, xwA4, xwB0, xwB1, xwB2, xwB3, xwB4;
    if (grp == 1 || grp == 2) {
        const int   gA = (grp == 1) ? 0 : 2;
        const float sA = (grp == 2) ? (2.0f * L2E) : L2E;  // gate g gets 2*log2e
        const float sB = L2E;                              // gates f,o
        const float* rA = w_ih1 + (gA * HIDN + k) * IND;
        const float* rB = w_ih1 + ((gA + 1) * HIDN + k) * IND;
        xwA0 = pk2(sA * rA[0], sA * rA[1]); xwA1 = pk2(sA * rA[2], sA * rA[3]);
        xwA2 = pk2(sA * rA[4], sA * rA[5]); xwA3 = pk2(sA * rA[6], sA * rA[7]);
        xwA4 = pk2(sA * rA[8], 0.0f);
        xwB0 = pk2(sB * rB[0], sB * rB[1]); xwB1 = pk2(sB * rB[2], sB * rB[3]);
        xwB2 = pk2(sB * rB[4], sB * rB[5]); xwB3 = pk2(sB * rB[6], sB * rB[7]);
        xwB4 = pk2(sB * rB[8], 0.0f);
    } else {
        xwA0 = h2zero(); xwA1 = h2zero(); xwA2 = h2zero(); xwA3 = h2zero();
        xwA4 = h2zero(); xwB0 = h2zero(); xwB1 = h2zero(); xwB2 = h2zero();
        xwB3 = h2zero(); xwB4 = h2zero();
    }

    const unsigned* hu = hc32 + ((lane < 40) ? 0 : 16);
    const bool  isl2   = (lane >= 20 && lane < 40);
    const float m2     = isl2 ? 1.0f : 0.0f;
    const float m1     = (grp == 0) ? 1.0f : 0.0f;
    const int   h2col  = lane - 20;
    const int   hidx16 = (lane < 20) ? lane : (32 + h2col);
    const int   shsrc  = (lane + 20) & 63;
    // ring read offset: L1 lanes read their unit (stride-2 words, 2-way max);
    // all other lanes read a wave-uniform address (broadcast, conflict-free)
    const int   rk2    = (grp == 0) ? (k * 2) : 0;

    // ring write base + slot stride (0 for non-writers -> scratch, fixed):
    // plane 0 (gates i,f) by grp1, plane 1 (gates g,o) by grp2
    unsigned* xg_wb = wls + ((grp == 1) ? (RING_OFF + k * 2)
                          : (grp == 2) ? (RING_OFF + 40 + k * 2)
                          : (SCR_OFF + lane * 2));
    const int pstride = (grp == 1 || grp == 2) ? 80 : 0;

    // fused projection weights (DPP sum over all lanes; wp nonzero on isl2)
    const float wp = isl2 ? w_p[h2col] : 0.0f;
    const float bp = b_p[0];

    float c = 0.0f, h = 0.0f;
    LDS_ORDER();                 // staging + hc zeros ordered before reads

    // ---- pipeline prologue: xg[row 0] -> ring slot 0 ("step -1"'s XPIPE)
    XPIPE(-1)
    LDS_ORDER();

    // ---- peel (i = 0): h is zero so h-dots vanish; gates = xg + bias
    STEP_P(0)
    // post-peel: zero the layer-2 chain state (layer 2 lags layer 1)
    c *= m1; h *= m1;
    if (lane < 40) hc16[hidx16] = (_Float16)h;
    LDS_ORDER();

    // ---- warm loop (no output): 12 steps (0 for chunk 0)
#pragma unroll 4
    for (int i = 1; i <= nwarm; ++i) {
        STEP_P(i)
    }

    // ---- output loop: 64 steps; step j emits h2[t0+j-1] via DPP wave-sum
#pragma unroll 4
    for (int j = 1; j <= CHUNK; ++j) {
        STEP_P(nwarm + j)
        float pr = wave_sum63(wp * h);
        if (lane == 63) out[t0 + j - 1] = pr + bp;
    }
}

extern "C" void kernel_launch(void* const* d_in, const int* in_sizes, int n_in,
                              void* d_out, int out_size, void* d_ws, size_t ws_size,
                              hipStream_t stream) {
    const float* x     = (const float*)d_in[0];
    const float* w_ih1 = (const float*)d_in[1];
    const float* w_hh1 = (const float*)d_in[2];
    const float* b1    = (const float*)d_in[3];
    const float* w_ih2 = (const float*)d_in[4];
    const float* w_hh2 = (const float*)d_in[5];
    const float* b2    = (const float*)d_in[6];
    const float* w_p   = (const float*)d_in[7];
    const float* b_p   = (const float*)d_in[8];
    float* out = (float*)d_out;
    (void)d_ws; (void)ws_size;   // fused kernel: no workspace needed

    lstm_fused6<<<NWG, 256, 0, stream>>>(x, w_ih1, w_hh1, b1,
                                         w_ih2, w_hh2, b2, w_p, b_p, out);
}